// Round 6
// baseline (37.709 us; speedup 1.0000x reference)
//
#include <hip/hip_runtime.h>

// MaxUnpool2D: in [16,64,64,128] f32, mask [16,64,64,128] i32 (flat NHWC index
// with Ho=128, Wo=128, guaranteed inside the 2x2 window of each input elem),
// out [16,128,128,128] f32.
//
// R6: R4 gather structure (best: 33.81 us) + NT on LOADS ONLY.
// R3 (NT both) lost 10% -> store-side nt defeats L2 write-combining.
// R5 (persistent blocks) lost 6% -> HW prefers many short streams.
// Input/mask are read-once: nt loads keep them out of L2, freeing it
// entirely for the write stream.

typedef float f32x4 __attribute__((ext_vector_type(4)));
typedef int   i32x4 __attribute__((ext_vector_type(4)));

__global__ __launch_bounds__(256) void MaxUnpool2D_59047210385945_kernel(
    const f32x4* __restrict__ in, const i32x4* __restrict__ mask,
    f32x4* __restrict__ out) {
    // Grid: 16(b) x 64(h) x 32(wc) = 32768 blocks.
    int bid = blockIdx.x;
    int wc = bid & 31;          // 4-wo chunk
    int h  = (bid >> 5) & 63;   // input row
    int b  = bid >> 11;

    int tid = threadIdx.x;
    int c4 = tid & 31;          // float4 channel group (C/4 = 32)
    int wl = (tid >> 5) & 3;    // wo within chunk
    int dh = tid >> 7;          // output row parity

    int wo = (wc << 2) + wl;
    int w  = wo >> 1;
    int dw = wo & 1;
    int ho = (h << 1) + dh;

    // input float4 index: ((b*64 + h)*64 + w)*32 + c4
    int iin = ((((b << 6) + h) << 6) + w);
    iin = (iin << 5) + c4;

    f32x4 v = __builtin_nontemporal_load(&in[iin]);
    i32x4 m = __builtin_nontemporal_load(&mask[iin]);

    f32x4 o;
    #pragma unroll
    for (int k = 0; k < 4; ++k) {
        // selected slot: bit14 of mask = dh, bit7 = dw
        int sel_dh = (m[k] >> 14) & 1;
        int sel_dw = (m[k] >> 7) & 1;
        o[k] = (sel_dh == dh && sel_dw == dw) ? v[k] : 0.0f;
    }

    // output float4 index: ((b*128 + ho)*128 + wo)*32 + c4
    int iout = ((((b << 7) + ho) << 7) + wo);
    iout = (iout << 5) + c4;

    out[iout] = o;   // normal store: keep L2 write-combining path
}

extern "C" void kernel_launch(void* const* d_in, const int* in_sizes, int n_in,
                              void* d_out, int out_size, void* d_ws, size_t ws_size,
                              hipStream_t stream) {
    const f32x4* in   = (const f32x4*)d_in[0];
    const i32x4* mask = (const i32x4*)d_in[1];
    f32x4*       out  = (f32x4*)d_out;

    // 16*64*32 = 32768 blocks x 256 threads = 8,388,608 threads = out float4s
    MaxUnpool2D_59047210385945_kernel<<<32768, 256, 0, stream>>>(in, mask, out);
}

// Round 7
// 34.033 us; speedup vs baseline: 1.1080x; 1.1080x over previous
//
#include <hip/hip_runtime.h>

// MaxUnpool2D: in [16,64,64,128] f32, mask [16,64,64,128] i32 (flat NHWC index
// with Ho=128, Wo=128, guaranteed inside the 2x2 window of each input elem),
// out [16,128,128,128] f32.
//
// FINAL (= R4, best at 33.81 us = 5.95 TB/s effective, 94.6% of the 6.29 TB/s
// copy ceiling on a 1:2 R:W mix):
// Output-centric GATHER. Each thread owns one OUTPUT float4 (b,ho,wo,c4),
// reads the corresponding input/mask float4 at (b,ho/2,wo/2,c4), and writes
// value-or-zero depending on whether the mask selects (ho&1, wo&1). Writes are
// perfectly contiguous (1 KB per wave-instruction); the 4x read reuse stays
// in-block (lanes 0-31/32-63 of a wave = dw 0/1 of the same input line; the
// dh=0 and dh=1 waves share the block's 4 KB input working set via L1/L2).
//
// Ruled out by measurement:
//   R3: NT load+store  -10%  (nt store defeats L2 write-combining)
//   R5: persistent/streaming blocks  -6%  (HW prefers many short streams)
//   R6: NT loads only  -11%  (nt load path slower; no pollution to save)

typedef float f32x4 __attribute__((ext_vector_type(4)));
typedef int   i32x4 __attribute__((ext_vector_type(4)));

__global__ __launch_bounds__(256) void MaxUnpool2D_59047210385945_kernel(
    const f32x4* __restrict__ in, const i32x4* __restrict__ mask,
    f32x4* __restrict__ out) {
    // Grid: 16(b) x 64(h) x 32(wc) = 32768 blocks.
    int bid = blockIdx.x;
    int wc = bid & 31;          // 4-wo chunk
    int h  = (bid >> 5) & 63;   // input row
    int b  = bid >> 11;

    int tid = threadIdx.x;
    int c4 = tid & 31;          // float4 channel group (C/4 = 32)
    int wl = (tid >> 5) & 3;    // wo within chunk
    int dh = tid >> 7;          // output row parity

    int wo = (wc << 2) + wl;
    int w  = wo >> 1;
    int dw = wo & 1;
    int ho = (h << 1) + dh;

    // input float4 index: ((b*64 + h)*64 + w)*32 + c4
    int iin = ((((b << 6) + h) << 6) + w);
    iin = (iin << 5) + c4;

    f32x4 v = in[iin];
    i32x4 m = mask[iin];

    f32x4 o;
    #pragma unroll
    for (int k = 0; k < 4; ++k) {
        // selected slot: bit14 of mask = dh, bit7 = dw
        int sel_dh = (m[k] >> 14) & 1;
        int sel_dw = (m[k] >> 7) & 1;
        o[k] = (sel_dh == dh && sel_dw == dw) ? v[k] : 0.0f;
    }

    // output float4 index: ((b*128 + ho)*128 + wo)*32 + c4
    int iout = ((((b << 7) + ho) << 7) + wo);
    iout = (iout << 5) + c4;

    out[iout] = o;
}

extern "C" void kernel_launch(void* const* d_in, const int* in_sizes, int n_in,
                              void* d_out, int out_size, void* d_ws, size_t ws_size,
                              hipStream_t stream) {
    const f32x4* in   = (const f32x4*)d_in[0];
    const i32x4* mask = (const i32x4*)d_in[1];
    f32x4*       out  = (f32x4*)d_out;

    // 16*64*32 = 32768 blocks x 256 threads = 8,388,608 threads = out float4s
    MaxUnpool2D_59047210385945_kernel<<<32768, 256, 0, stream>>>(in, mask, out);
}